// Round 6
// baseline (2662.791 us; speedup 1.0000x reference)
//
#include <hip/hip_runtime.h>
#include <hip/hip_bf16.h>
#include <cstdint>
#include <cstddef>

#define NNODES 50000
#define NEDGES 800000
#define NREL 8
#define DIM 128
#define KDIM (NREL * DIM)  // 1024
#define NEG_SLOPE 0.2f

typedef __attribute__((ext_vector_type(8))) short short8;
typedef __attribute__((ext_vector_type(4))) float f32x4;

// bf16 helpers (RNE, matches __float2bfloat16 for normal inputs)
static __device__ __forceinline__ short f2bf(float v) {
  union { float f; unsigned u; } c; c.f = v;
  unsigned u = c.u;
  unsigned r = (u + 0x7fffu + ((u >> 16) & 1u)) >> 16;
  return (short)r;
}
static __device__ __forceinline__ float bf2f(short s) {
  union { unsigned u; float f; } c; c.u = ((unsigned)(unsigned short)s) << 16;
  return c.f;
}

// ======================= preprocessing: CSR by (etype, dst) =======================

__global__ void k_hist(const int* __restrict__ ei, const int* __restrict__ et,
                       int* __restrict__ cnt, int E) {
  int e = blockIdx.x * 256 + threadIdx.x;
  if (e < E) {
    int d = ei[E + e];
    int t = et[e];
    atomicAdd(&cnt[t * NNODES + d], 1);
  }
}

__global__ void k_scan_reduce(const int* __restrict__ cnt, int* __restrict__ sums, int n) {
  __shared__ int sd[256];
  int base = blockIdx.x * 4096;
  int t = threadIdx.x;
  int acc = 0;
  for (int i = t; i < 4096; i += 256) {
    int idx = base + i;
    if (idx < n) acc += cnt[idx];
  }
  sd[t] = acc; __syncthreads();
  for (int s = 128; s > 0; s >>= 1) {
    if (t < s) sd[t] += sd[t + s];
    __syncthreads();
  }
  if (t == 0) sums[blockIdx.x] = sd[0];
}

__global__ void k_scan_top(int* sums, int nb) {
  if (threadIdx.x == 0 && blockIdx.x == 0) {
    int run = 0;
    for (int i = 0; i < nb; i++) { int v = sums[i]; sums[i] = run; run += v; }
  }
}

__global__ void k_scan_final(const int* __restrict__ cnt, const int* __restrict__ sums,
                             int* __restrict__ offs, int n, int E) {
  __shared__ int sd[256];
  int base = blockIdx.x * 4096;
  int t = threadIdx.x;
  int run = sums[blockIdx.x];
  for (int c = 0; c < 16; c++) {
    int idx = base + c * 256 + t;
    int v = (idx < n) ? cnt[idx] : 0;
    sd[t] = v; __syncthreads();
    for (int s = 1; s < 256; s <<= 1) {
      int u = (t >= s) ? sd[t - s] : 0;
      __syncthreads();
      sd[t] += u;
      __syncthreads();
    }
    if (idx < n) offs[idx] = run + sd[t] - v;  // exclusive
    run += sd[255];
    __syncthreads();
  }
  if (blockIdx.x == 0 && t == 0) offs[n] = E;
}

__global__ void k_scatter(const int* __restrict__ ei, const int* __restrict__ et,
                          int* __restrict__ cursor, int* __restrict__ pk, int E) {
  int e = blockIdx.x * 256 + threadIdx.x;
  if (e < E) {
    int s = ei[e];       // src < 50000 fits in 16 bits
    int d = ei[E + e];   // dst < 50000 fits in 16 bits
    int t = et[e];
    int pos = atomicAdd(&cursor[t * NNODES + d], 1);
    pk[pos] = s | (d << 16);
  }
}

// ======================= per-layer kernels =======================

// Split W [1024,128] fp32 into MFMA-fragment-major bf16 hi/lo planes:
// Wf id = r*2048 + kc*512 + ng*64 + l (short8 units): n = ng*16 + (l&15),
// k = r*128 + kc*32 + (l>>4)*8 + j  (j=0..7).
__global__ void k_splitW_frag(const float* __restrict__ W, short* __restrict__ Wfh,
                              short* __restrict__ Wfl) {
  int id = blockIdx.x * 256 + threadIdx.x;  // 0..16383
  if (id >= 16384) return;
  int l = id & 63;
  int ng = (id >> 6) & 7;
  int kc = (id >> 9) & 3;
  int r = id >> 11;
  int n = ng * 16 + (l & 15);
  int k0 = r * 128 + kc * 32 + (l >> 4) * 8;
  short8 vh, vl;
#pragma unroll
  for (int j = 0; j < 8; j++) {
    float v = W[(size_t)(k0 + j) * DIM + n];
    short h = f2bf(v);
    vh[j] = h;
    vl[j] = f2bf(v - bf2f(h));
  }
  ((short8*)Wfh)[id] = vh;
  ((short8*)Wfl)[id] = vl;
}

// wq[r][c] = sum_d W[r][c][d]*q[d] ; wk likewise. 2048 outputs.
__global__ void k_wqk(const float* __restrict__ W, const float* __restrict__ q,
                      const float* __restrict__ k, float* __restrict__ wq,
                      float* __restrict__ wk) {
  int id = blockIdx.x * 256 + threadIdx.x;  // 0..2047
  if (id >= 2 * NREL * DIM) return;
  int which = id >> 10;       // 0 = q, 1 = k
  int rc = id & 1023;         // r*128 + c
  const float* wrow = W + (size_t)rc * DIM;
  const float* v = which ? k : q;
  float acc = 0.f;
#pragma unroll 8
  for (int d = 0; d < DIM; d++) acc += wrow[d] * v[d];
  (which ? wk : wq)[rc] = acc;
}

// qp[n][r] = x[n]·wq[r], kp[n][r] = x[n]·wk[r]. One wave per node.
__global__ void k_qk(const float* __restrict__ x, const float* __restrict__ wq,
                     const float* __restrict__ wk, float* __restrict__ qp,
                     float* __restrict__ kp, int N) {
  int wid = (blockIdx.x * blockDim.x + threadIdx.x) >> 6;
  int lane = threadIdx.x & 63;
  if (wid >= N) return;
  float x0 = x[(size_t)wid * DIM + lane];
  float x1 = x[(size_t)wid * DIM + 64 + lane];
#pragma unroll
  for (int r = 0; r < NREL; r++) {
    float aq = x0 * wq[r * DIM + lane] + x1 * wq[r * DIM + 64 + lane];
    float ak = x0 * wk[r * DIM + lane] + x1 * wk[r * DIM + 64 + lane];
    for (int s = 32; s > 0; s >>= 1) {
      aq += __shfl_xor(aq, s);
      ak += __shfl_xor(ak, s);
    }
    if (lane == 0) {
      qp[(size_t)wid * NREL + r] = aq;
      kp[(size_t)wid * NREL + r] = ak;
    }
  }
}

// Per-node across-relation softmax -> per-edge weight wgt[i] in (r,dst) order.
// One wave per node; lanes split 8-per-relation over the node's 8 edge ranges.
__global__ void k_alpha(const float* __restrict__ qp, const float* __restrict__ kp,
                        const int* __restrict__ offs2, const int* __restrict__ pk2,
                        float* __restrict__ wgt2, int N) {
  int wid = (blockIdx.x * blockDim.x + threadIdx.x) >> 6;
  int lane = threadIdx.x & 63;
  if (wid >= N) return;
  int r = lane >> 3, j = lane & 7;
  int e0 = offs2[r * N + wid];
  int e1 = offs2[r * N + wid + 1];  // flat monotone key r*N+n; valid at n=N-1
  float qv = qp[wid * NREL + r];
  float m = -1e30f;
  for (int i = e0 + j; i < e1; i += 8) {
    int src = pk2[i] & 0xffff;
    float a = qv + kp[src * NREL + r];
    a = (a > 0.f) ? a : NEG_SLOPE * a;
    m = fmaxf(m, a);
  }
  for (int s = 32; s > 0; s >>= 1) m = fmaxf(m, __shfl_xor(m, s));
  float ssum = 0.f;
  for (int i = e0 + j; i < e1; i += 8) {
    int src = pk2[i] & 0xffff;
    float a = qv + kp[src * NREL + r];
    a = (a > 0.f) ? a : NEG_SLOPE * a;
    float e = expf(a - m);
    wgt2[i] = e;
    ssum += e;
  }
  for (int s = 32; s > 0; s >>= 1) ssum += __shfl_xor(ssum, s);
  float inv = 1.f / (ssum + 1e-16f);
  for (int i = e0 + j; i < e1; i += 8) wgt2[i] *= inv;
}

// ======================= fused aggregation + split-bf16 MFMA GEMM =======================
// Per block: 64 dst nodes. Per relation: edge-parallel gather into fp32 LDS tile
// (ds atomics, 4-deep ILP), then MFMA with on-the-fly hi/lo split.
#define SPITCH 132  // fp32 words per LDS row: 128 data + 4 pad (132%32=4 -> even banks)

__global__ __launch_bounds__(256, 4) void k_fused(
    const float* __restrict__ x, const int* __restrict__ offs2,
    const int* __restrict__ pk2, const float* __restrict__ wgt2,
    const short* __restrict__ Wfh, const short* __restrict__ Wfl,
    const float* __restrict__ bias, float* __restrict__ out, int M, int relu) {
  __shared__ float sS[64 * SPITCH];
  int t = threadIdx.x;
  int w = t >> 6, l = t & 63;
  int m0 = blockIdx.x * 64;
  int mEnd = m0 + 64; if (mEnd > M) mEnd = M;

  f32x4 acc[4][2];
  f32x4 zero = {0.f, 0.f, 0.f, 0.f};
#pragma unroll
  for (int mt = 0; mt < 4; mt++)
#pragma unroll
    for (int nt = 0; nt < 2; nt++) acc[mt][nt] = zero;

  const char* wfh_base = (const char*)Wfh + ((size_t)(w * 2) * 64 + l) * 16;
  const char* wfl_base = (const char*)Wfl + ((size_t)(w * 2) * 64 + l) * 16;
  int r16 = l & 15, hi16 = l >> 4;

  for (int r = 0; r < NREL; r++) {
    // ---- zero the tile ----
    for (int i = t; i < 64 * SPITCH; i += 256) sS[i] = 0.f;
    __syncthreads();
    // ---- edge-parallel aggregation, 4-deep ILP per wave ----
    {
      int e0 = offs2[r * NNODES + m0];
      int e1 = offs2[r * NNODES + mEnd];
      int nE = e1 - e0;
      int chunk = (nE + 3) >> 2;
      int ws = e0 + w * chunk;
      int we = ws + chunk; if (we > e1) we = e1;
      for (int base = ws; base < we; base += 4) {
        int n4 = we - base; if (n4 > 4) n4 = 4;
        int p[4]; float wg[4]; float2 xv[4];
#pragma unroll
        for (int u = 0; u < 4; u++) {
          int idx = base + ((u < n4) ? u : 0);
          p[u] = pk2[idx];
          wg[u] = wgt2[idx];
        }
#pragma unroll
        for (int u = 0; u < 4; u++) {
          int src = p[u] & 0xffff;
          xv[u] = ((const float2*)(x + (size_t)src * DIM))[l];
        }
#pragma unroll
        for (int u = 0; u < 4; u++) {
          if (u < n4) {
            int row = (int)(((unsigned)p[u]) >> 16) - m0;
            atomicAdd(&sS[row * SPITCH + 2 * l], wg[u] * xv[u].x);
            atomicAdd(&sS[row * SPITCH + 2 * l + 1], wg[u] * xv[u].y);
          }
        }
      }
    }
    __syncthreads();
    // ---- MFMA: K=128 for this relation, 4 chunks of 32, split hi/lo on the fly ----
#pragma unroll
    for (int kc = 0; kc < 4; kc++) {
      size_t wfoff = (size_t)((r * 4 + kc) * 8) * 1024;  // bytes
      short8 fwh[2], fwl[2];
#pragma unroll
      for (int nt = 0; nt < 2; nt++) {
        fwh[nt] = *(const short8*)(wfh_base + wfoff + (size_t)nt * 1024);
        fwl[nt] = *(const short8*)(wfl_base + wfoff + (size_t)nt * 1024);
      }
      short8 fsh[4], fsl[4];
#pragma unroll
      for (int mt = 0; mt < 4; mt++) {
        const float* ps = &sS[(mt * 16 + r16) * SPITCH + kc * 32 + hi16 * 8];
        f32x4 va = *(const f32x4*)ps;
        f32x4 vb = *(const f32x4*)(ps + 4);
        short8 hh, ll;
#pragma unroll
        for (int jj = 0; jj < 4; jj++) {
          short h = f2bf(va[jj]);
          hh[jj] = h; ll[jj] = f2bf(va[jj] - bf2f(h));
        }
#pragma unroll
        for (int jj = 0; jj < 4; jj++) {
          short h = f2bf(vb[jj]);
          hh[4 + jj] = h; ll[4 + jj] = f2bf(vb[jj] - bf2f(h));
        }
        fsh[mt] = hh; fsl[mt] = ll;
      }
#pragma unroll
      for (int mt = 0; mt < 4; mt++)
#pragma unroll
        for (int nt = 0; nt < 2; nt++) {
          acc[mt][nt] = __builtin_amdgcn_mfma_f32_16x16x32_bf16(fwh[nt], fsh[mt], acc[mt][nt], 0, 0, 0);
          acc[mt][nt] = __builtin_amdgcn_mfma_f32_16x16x32_bf16(fwh[nt], fsl[mt], acc[mt][nt], 0, 0, 0);
          acc[mt][nt] = __builtin_amdgcn_mfma_f32_16x16x32_bf16(fwl[nt], fsh[mt], acc[mt][nt], 0, 0, 0);
        }
    }
    __syncthreads();
  }
  // ---- epilogue: C col(l&15)=m offset, row((l>>4)*4+j)=n offset ----
#pragma unroll
  for (int mt = 0; mt < 4; mt++) {
    int m = m0 + mt * 16 + r16;
    if (m >= M) continue;
#pragma unroll
    for (int nt = 0; nt < 2; nt++) {
      int n = w * 32 + nt * 16 + hi16 * 4;
      float4 bv = *(const float4*)(bias + n);
      f32x4 a = acc[mt][nt];
      float4 o;
      o.x = a.x + bv.x; o.y = a.y + bv.y; o.z = a.z + bv.z; o.w = a.w + bv.w;
      if (relu) {
        o.x = fmaxf(o.x, 0.f); o.y = fmaxf(o.y, 0.f);
        o.z = fmaxf(o.z, 0.f); o.w = fmaxf(o.w, 0.f);
      }
      *(float4*)(out + (size_t)m * DIM + n) = o;
    }
  }
}

// ======================= launcher =======================

extern "C" void kernel_launch(void* const* d_in, const int* in_sizes, int n_in,
                              void* d_out, int out_size, void* d_ws, size_t ws_size,
                              hipStream_t stream) {
  const float* x = (const float*)d_in[0];
  const int* ei = (const int*)d_in[1];
  const int* et = (const int*)d_in[2];
  const float* Wl3[3] = {(const float*)d_in[3], (const float*)d_in[7], (const float*)d_in[11]};
  const float* ql[3] = {(const float*)d_in[4], (const float*)d_in[8], (const float*)d_in[12]};
  const float* kl[3] = {(const float*)d_in[5], (const float*)d_in[9], (const float*)d_in[13]};
  const float* bl[3] = {(const float*)d_in[6], (const float*)d_in[10], (const float*)d_in[14]};
  float* out = (float*)d_out;

  char* w = (char*)d_ws;
  auto alloc = [&](size_t bytes) -> char* {
    char* p = w;
    w += (bytes + 255) & ~(size_t)255;
    return p;
  };
  const int NK = NREL * NNODES;
  int* cnt = (int*)alloc((size_t)NK * 4);
  int* offs2 = (int*)alloc((size_t)(NK + 1) * 4);
  int* cursor = (int*)alloc((size_t)NK * 4);
  int* sums = (int*)alloc(256 * 4);
  int* pk2 = (int*)alloc((size_t)NEDGES * 4);
  float* wq = (float*)alloc((size_t)NREL * DIM * 4);
  float* wk = (float*)alloc((size_t)NREL * DIM * 4);
  float* qp = (float*)alloc((size_t)NNODES * NREL * 4);
  float* kp = (float*)alloc((size_t)NNODES * NREL * 4);
  float* wgt2 = (float*)alloc((size_t)NEDGES * 4);
  short* Wfh = (short*)alloc((size_t)KDIM * DIM * 2);
  short* Wfl = (short*)alloc((size_t)KDIM * DIM * 2);
  float* h1 = (float*)alloc((size_t)NNODES * DIM * 4);
  float* h2 = (float*)alloc((size_t)NNODES * DIM * 4);

  // ---- build CSR sorted by (etype, dst), once (shared by all 3 layers) ----
  hipMemsetAsync(cnt, 0, (size_t)NK * 4, stream);
  k_hist<<<(NEDGES + 255) / 256, 256, 0, stream>>>(ei, et, cnt, NEDGES);
  int nchunk = (NK + 4095) / 4096;  // 98
  k_scan_reduce<<<nchunk, 256, 0, stream>>>(cnt, sums, NK);
  k_scan_top<<<1, 64, 0, stream>>>(sums, nchunk);
  k_scan_final<<<nchunk, 256, 0, stream>>>(cnt, sums, offs2, NK, NEDGES);
  hipMemcpyAsync(cursor, offs2, (size_t)NK * 4, hipMemcpyDeviceToDevice, stream);
  k_scatter<<<(NEDGES + 255) / 256, 256, 0, stream>>>(ei, et, cursor, pk2, NEDGES);

  // ---- 3 RGAT layers ----
  const float* hin = x;
  float* houts[3] = {h1, h2, out};
  for (int l = 0; l < 3; l++) {
    k_splitW_frag<<<64, 256, 0, stream>>>(Wl3[l], Wfh, Wfl);
    k_wqk<<<(2 * NREL * DIM + 255) / 256, 256, 0, stream>>>(Wl3[l], ql[l], kl[l], wq, wk);
    k_qk<<<(NNODES + 3) / 4, 256, 0, stream>>>(hin, wq, wk, qp, kp, NNODES);
    k_alpha<<<(NNODES + 3) / 4, 256, 0, stream>>>(qp, kp, offs2, pk2, wgt2, NNODES);
    k_fused<<<(NNODES + 63) / 64, 256, 0, stream>>>(hin, offs2, pk2, wgt2, Wfh, Wfl,
                                                    bl[l], houts[l], NNODES, l < 2 ? 1 : 0);
    hin = houts[l];
  }
}

// Round 7
// 946.133 us; speedup vs baseline: 2.8144x; 2.8144x over previous
//
#include <hip/hip_runtime.h>
#include <hip/hip_bf16.h>
#include <cstdint>
#include <cstddef>

#define NNODES 50000
#define NEDGES 800000
#define NREL 8
#define DIM 128
#define NOUT 1024  // NREL*DIM concat output dim of k_xr
#define NEG_SLOPE 0.2f

typedef __attribute__((ext_vector_type(8))) short short8;
typedef __attribute__((ext_vector_type(4))) float f32x4;

// bf16 helpers (RNE)
static __device__ __forceinline__ short f2bf(float v) {
  union { float f; unsigned u; } c; c.f = v;
  unsigned u = c.u;
  unsigned r = (u + 0x7fffu + ((u >> 16) & 1u)) >> 16;
  return (short)r;
}
static __device__ __forceinline__ float bf2f(short s) {
  union { unsigned u; float f; } c; c.u = ((unsigned)(unsigned short)s) << 16;
  return c.f;
}

// ======================= preprocessing: CSR by (dst, etype) =======================

__global__ void k_hist(const int* __restrict__ ei, const int* __restrict__ et,
                       int* __restrict__ cnt, int E) {
  int e = blockIdx.x * 256 + threadIdx.x;
  if (e < E) {
    int d = ei[E + e];
    int t = et[e];
    atomicAdd(&cnt[d * NREL + t], 1);
  }
}

__global__ void k_scan_reduce(const int* __restrict__ cnt, int* __restrict__ sums, int n) {
  __shared__ int sd[256];
  int base = blockIdx.x * 4096;
  int t = threadIdx.x;
  int acc = 0;
  for (int i = t; i < 4096; i += 256) {
    int idx = base + i;
    if (idx < n) acc += cnt[idx];
  }
  sd[t] = acc; __syncthreads();
  for (int s = 128; s > 0; s >>= 1) {
    if (t < s) sd[t] += sd[t + s];
    __syncthreads();
  }
  if (t == 0) sums[blockIdx.x] = sd[0];
}

__global__ void k_scan_top(int* sums, int nb) {
  if (threadIdx.x == 0 && blockIdx.x == 0) {
    int run = 0;
    for (int i = 0; i < nb; i++) { int v = sums[i]; sums[i] = run; run += v; }
  }
}

__global__ void k_scan_final(const int* __restrict__ cnt, const int* __restrict__ sums,
                             int* __restrict__ offs, int n, int E) {
  __shared__ int sd[256];
  int base = blockIdx.x * 4096;
  int t = threadIdx.x;
  int run = sums[blockIdx.x];
  for (int c = 0; c < 16; c++) {
    int idx = base + c * 256 + t;
    int v = (idx < n) ? cnt[idx] : 0;
    sd[t] = v; __syncthreads();
    for (int s = 1; s < 256; s <<= 1) {
      int u = (t >= s) ? sd[t - s] : 0;
      __syncthreads();
      sd[t] += u;
      __syncthreads();
    }
    if (idx < n) offs[idx] = run + sd[t] - v;  // exclusive
    run += sd[255];
    __syncthreads();
  }
  if (blockIdx.x == 0 && t == 0) offs[n] = E;
}

__global__ void k_scatter(const int* __restrict__ ei, const int* __restrict__ et,
                          int* __restrict__ cursor, int* __restrict__ pk, int E) {
  int e = blockIdx.x * 256 + threadIdx.x;
  if (e < E) {
    int s = ei[e];       // src < 50000 fits in 16 bits
    int d = ei[E + e];
    int t = et[e];
    int pos = atomicAdd(&cursor[d * NREL + t], 1);
    pk[pos] = s | (t << 16);
  }
}

// ======================= per-layer kernels =======================

// Split Wcat [128, 1024] (Wcat[k][r*128+n] = W[r][k][n]) into MFMA-fragment-major
// bf16 hi/lo planes. Frag id = (n16*4 + kc)*64 + l (short8 units):
// n = n16*16 + (l&15), k = kc*32 + (l>>4)*8 + j.
__global__ void k_splitW_frag(const float* __restrict__ W, short* __restrict__ Wfh,
                              short* __restrict__ Wfl) {
  int id = blockIdx.x * 256 + threadIdx.x;  // 0..16383
  if (id >= 16384) return;
  int l = id & 63;
  int kc = (id >> 6) & 3;
  int n16 = id >> 8;
  int n = n16 * 16 + (l & 15);      // 0..1023
  int r = n >> 7, nn = n & 127;
  int k0 = kc * 32 + (l >> 4) * 8;  // 0..127
  short8 vh, vl;
#pragma unroll
  for (int j = 0; j < 8; j++) {
    float v = W[((size_t)r * DIM + k0 + j) * DIM + nn];
    short h = f2bf(v);
    vh[j] = h;
    vl[j] = f2bf(v - bf2f(h));
  }
  ((short8*)Wfh)[id] = vh;
  ((short8*)Wfl)[id] = vl;
}

// wq[r][c] = sum_d W[r][c][d]*q[d] ; wk likewise. 2048 outputs.
__global__ void k_wqk(const float* __restrict__ W, const float* __restrict__ q,
                      const float* __restrict__ k, float* __restrict__ wq,
                      float* __restrict__ wk) {
  int id = blockIdx.x * 256 + threadIdx.x;  // 0..2047
  if (id >= 2 * NREL * DIM) return;
  int which = id >> 10;       // 0 = q, 1 = k
  int rc = id & 1023;         // r*128 + c
  const float* wrow = W + (size_t)rc * DIM;
  const float* v = which ? k : q;
  float acc = 0.f;
#pragma unroll 8
  for (int d = 0; d < DIM; d++) acc += wrow[d] * v[d];
  (which ? wk : wq)[rc] = acc;
}

// qp[n][r] = x[n]·wq[r], kp[n][r] = x[n]·wk[r]. One wave per node.
__global__ void k_qk(const float* __restrict__ x, const float* __restrict__ wq,
                     const float* __restrict__ wk, float* __restrict__ qp,
                     float* __restrict__ kp, int N) {
  int wid = (blockIdx.x * blockDim.x + threadIdx.x) >> 6;
  int lane = threadIdx.x & 63;
  if (wid >= N) return;
  float x0 = x[(size_t)wid * DIM + lane];
  float x1 = x[(size_t)wid * DIM + 64 + lane];
#pragma unroll
  for (int r = 0; r < NREL; r++) {
    float aq = x0 * wq[r * DIM + lane] + x1 * wq[r * DIM + 64 + lane];
    float ak = x0 * wk[r * DIM + lane] + x1 * wk[r * DIM + 64 + lane];
    for (int s = 32; s > 0; s >>= 1) {
      aq += __shfl_xor(aq, s);
      ak += __shfl_xor(ak, s);
    }
    if (lane == 0) {
      qp[(size_t)wid * NREL + r] = aq;
      kp[(size_t)wid * NREL + r] = ak;
    }
  }
}

// ======================= k_xr: xr = hin @ Wcat, split-bf16 MFMA =======================
// [M=50000,K=128] @ [128,1024] -> fp32 xr [M][1024] (= [m][r*128+c]).
// Block: 64m x 256n tile; 4 waves, wave w covers n in [nb*256 + w*64, +64).
#define XR_SPITCH 132  // fp32 words per LDS row

__global__ __launch_bounds__(256, 3) void k_xr(
    const float* __restrict__ A, const short* __restrict__ Wfh,
    const short* __restrict__ Wfl, float* __restrict__ xr, int M) {
  __shared__ float sA[64 * XR_SPITCH];
  int t = threadIdx.x, w = t >> 6, l = t & 63;
  int m0 = blockIdx.x * 64;
  int nb = blockIdx.y;  // 0..3
  // ---- stage A tile: 64 rows x 128 floats ----
  {
    int row = t >> 2, seg = t & 3;
    int m = m0 + row;
    const float* src = A + (size_t)m * DIM + seg * 32;
    float4 z = make_float4(0.f, 0.f, 0.f, 0.f);
#pragma unroll
    for (int q = 0; q < 8; q++) {
      float4 v = (m < M) ? *(const float4*)(src + q * 4) : z;
      *(float4*)(&sA[row * XR_SPITCH + seg * 32 + q * 4]) = v;
    }
  }
  __syncthreads();
  f32x4 acc[4][4];
  f32x4 zero = {0.f, 0.f, 0.f, 0.f};
#pragma unroll
  for (int mt = 0; mt < 4; mt++)
#pragma unroll
    for (int nt = 0; nt < 4; nt++) acc[mt][nt] = zero;

  int r16 = l & 15, hi16 = l >> 4;
  int n16base = nb * 16 + w * 4;
#pragma unroll
  for (int kc = 0; kc < 4; kc++) {
    // A-frags (node feats) from LDS, split hi/lo on the fly
    short8 fsh[4], fsl[4];
#pragma unroll
    for (int mt = 0; mt < 4; mt++) {
      const float* ps = &sA[(mt * 16 + r16) * XR_SPITCH + kc * 32 + hi16 * 8];
      f32x4 va = *(const f32x4*)ps;
      f32x4 vb = *(const f32x4*)(ps + 4);
      short8 hh, ll;
#pragma unroll
      for (int jj = 0; jj < 4; jj++) {
        short h = f2bf(va[jj]);
        hh[jj] = h; ll[jj] = f2bf(va[jj] - bf2f(h));
      }
#pragma unroll
      for (int jj = 0; jj < 4; jj++) {
        short h = f2bf(vb[jj]);
        hh[4 + jj] = h; ll[4 + jj] = f2bf(vb[jj] - bf2f(h));
      }
      fsh[mt] = hh; fsl[mt] = ll;
    }
#pragma unroll
    for (int nt = 0; nt < 4; nt++) {
      size_t fid = ((size_t)(n16base + nt) * 4 + kc) * 64 + l;
      short8 ah = ((const short8*)Wfh)[fid];
      short8 al = ((const short8*)Wfl)[fid];
#pragma unroll
      for (int mt = 0; mt < 4; mt++) {
        acc[mt][nt] = __builtin_amdgcn_mfma_f32_16x16x32_bf16(ah, fsh[mt], acc[mt][nt], 0, 0, 0);
        acc[mt][nt] = __builtin_amdgcn_mfma_f32_16x16x32_bf16(ah, fsl[mt], acc[mt][nt], 0, 0, 0);
        acc[mt][nt] = __builtin_amdgcn_mfma_f32_16x16x32_bf16(al, fsh[mt], acc[mt][nt], 0, 0, 0);
      }
    }
  }
  // ---- epilogue: D col(l&15)=m, row((l>>4)*4+j)=n ----
#pragma unroll
  for (int mt = 0; mt < 4; mt++) {
    int m = m0 + mt * 16 + r16;
    if (m >= M) continue;
#pragma unroll
    for (int nt = 0; nt < 4; nt++) {
      int n = nb * 256 + w * 64 + nt * 16 + hi16 * 4;
      f32x4 a = acc[mt][nt];
      float4 o; o.x = a.x; o.y = a.y; o.z = a.z; o.w = a.w;
      *(float4*)(xr + (size_t)m * NOUT + n) = o;
    }
  }
}

// ======================= k_agg_out: softmax + gather-aggregate + bias/relu ==============
// One wave per dst node. out[n][c] = relu_opt( sum_e alpha_e * xr[src_e][t_e*128+c] + b[c] )
__global__ void k_agg_out(const float* __restrict__ xr, const float* __restrict__ qp,
                          const float* __restrict__ kp, const int* __restrict__ offs,
                          const int* __restrict__ pk, const float* __restrict__ bias,
                          float* __restrict__ out, int N, int relu) {
  int wid = (blockIdx.x * blockDim.x + threadIdx.x) >> 6;
  int lane = threadIdx.x & 63;
  if (wid >= N) return;
  int base = wid * NREL;
  int start = offs[base], end = offs[base + NREL];
  float a0 = 0.f, a1 = 0.f;
  if (start < end) {
    // pass 1: max of leaky_relu(qp[dst,t] + kp[src,t])
    float m = -1e30f;
    for (int i = start + lane; i < end; i += 64) {
      int p = pk[i];
      int src = p & 0xffff, tt = p >> 16;
      float a = qp[base + tt] + kp[src * NREL + tt];
      a = (a > 0.f) ? a : NEG_SLOPE * a;
      m = fmaxf(m, a);
    }
    for (int s = 32; s > 0; s >>= 1) m = fmaxf(m, __shfl_xor(m, s));
    // pass 2: sum of exp
    float ssum = 0.f;
    for (int i = start + lane; i < end; i += 64) {
      int p = pk[i];
      int src = p & 0xffff, tt = p >> 16;
      float a = qp[base + tt] + kp[src * NREL + tt];
      a = (a > 0.f) ? a : NEG_SLOPE * a;
      ssum += expf(a - m);
    }
    for (int s = 32; s > 0; s >>= 1) ssum += __shfl_xor(ssum, s);
    float inv = 1.f / (ssum + 1e-16f);
    // pass 3: weighted gather of xr rows, 2-deep pipeline
    for (int i = start; i < end; i += 2) {
      int p0 = pk[i];
      int has1 = (i + 1 < end);
      int p1 = pk[has1 ? i + 1 : i];
      int s0 = p0 & 0xffff, t0 = p0 >> 16;
      int s1 = p1 & 0xffff, t1 = p1 >> 16;
      // issue both gathers first
      float2 xv0 = ((const float2*)(xr + ((size_t)s0 * NREL + t0) * DIM))[lane];
      float2 xv1 = ((const float2*)(xr + ((size_t)s1 * NREL + t1) * DIM))[lane];
      float e0a = qp[base + t0] + kp[s0 * NREL + t0];
      e0a = (e0a > 0.f) ? e0a : NEG_SLOPE * e0a;
      float w0 = expf(e0a - m) * inv;
      float e1a = qp[base + t1] + kp[s1 * NREL + t1];
      e1a = (e1a > 0.f) ? e1a : NEG_SLOPE * e1a;
      float w1 = has1 ? (expf(e1a - m) * inv) : 0.f;
      a0 = fmaf(w0, xv0.x, a0);
      a1 = fmaf(w0, xv0.y, a1);
      a0 = fmaf(w1, xv1.x, a0);
      a1 = fmaf(w1, xv1.y, a1);
    }
  }
  float2 bv = ((const float2*)bias)[lane];
  a0 += bv.x; a1 += bv.y;
  if (relu) { a0 = fmaxf(a0, 0.f); a1 = fmaxf(a1, 0.f); }
  float2 o; o.x = a0; o.y = a1;
  ((float2*)(out + (size_t)wid * DIM))[lane] = o;
}

// ======================= launcher =======================

extern "C" void kernel_launch(void* const* d_in, const int* in_sizes, int n_in,
                              void* d_out, int out_size, void* d_ws, size_t ws_size,
                              hipStream_t stream) {
  const float* x = (const float*)d_in[0];
  const int* ei = (const int*)d_in[1];
  const int* et = (const int*)d_in[2];
  const float* Wl3[3] = {(const float*)d_in[3], (const float*)d_in[7], (const float*)d_in[11]};
  const float* ql[3] = {(const float*)d_in[4], (const float*)d_in[8], (const float*)d_in[12]};
  const float* kl[3] = {(const float*)d_in[5], (const float*)d_in[9], (const float*)d_in[13]};
  const float* bl[3] = {(const float*)d_in[6], (const float*)d_in[10], (const float*)d_in[14]};
  float* out = (float*)d_out;

  char* w = (char*)d_ws;
  auto alloc = [&](size_t bytes) -> char* {
    char* p = w;
    w += (bytes + 255) & ~(size_t)255;
    return p;
  };
  const int NK = NNODES * NREL;
  float* xr = (float*)alloc((size_t)NNODES * NOUT * 4);  // 204.8 MB
  int* cnt = (int*)alloc((size_t)NK * 4);
  int* offs = (int*)alloc((size_t)(NK + 1) * 4);
  int* cursor = (int*)alloc((size_t)NK * 4);
  int* sums = (int*)alloc(256 * 4);
  int* pk = (int*)alloc((size_t)NEDGES * 4);
  float* wq = (float*)alloc((size_t)NREL * DIM * 4);
  float* wk = (float*)alloc((size_t)NREL * DIM * 4);
  float* qp = (float*)alloc((size_t)NNODES * NREL * 4);
  float* kp = (float*)alloc((size_t)NNODES * NREL * 4);
  short* Wfh = (short*)alloc((size_t)DIM * NOUT * 2);
  short* Wfl = (short*)alloc((size_t)DIM * NOUT * 2);
  float* h1 = (float*)alloc((size_t)NNODES * DIM * 4);
  float* h2 = (float*)alloc((size_t)NNODES * DIM * 4);

  // ---- build CSR sorted by (dst, etype), once (shared by all 3 layers) ----
  hipMemsetAsync(cnt, 0, (size_t)NK * 4, stream);
  k_hist<<<(NEDGES + 255) / 256, 256, 0, stream>>>(ei, et, cnt, NEDGES);
  int nchunk = (NK + 4095) / 4096;  // 98
  k_scan_reduce<<<nchunk, 256, 0, stream>>>(cnt, sums, NK);
  k_scan_top<<<1, 64, 0, stream>>>(sums, nchunk);
  k_scan_final<<<nchunk, 256, 0, stream>>>(cnt, sums, offs, NK, NEDGES);
  hipMemcpyAsync(cursor, offs, (size_t)NK * 4, hipMemcpyDeviceToDevice, stream);
  k_scatter<<<(NEDGES + 255) / 256, 256, 0, stream>>>(ei, et, cursor, pk, NEDGES);

  // ---- 3 RGAT layers ----
  const float* hin = x;
  float* houts[3] = {h1, h2, out};
  for (int l = 0; l < 3; l++) {
    k_splitW_frag<<<64, 256, 0, stream>>>(Wl3[l], Wfh, Wfl);
    k_wqk<<<(2 * NREL * DIM + 255) / 256, 256, 0, stream>>>(Wl3[l], ql[l], kl[l], wq, wk);
    k_qk<<<(NNODES + 3) / 4, 256, 0, stream>>>(hin, wq, wk, qp, kp, NNODES);
    dim3 gxr((NNODES + 63) / 64, 4);
    k_xr<<<gxr, 256, 0, stream>>>(hin, Wfh, Wfl, xr, NNODES);
    k_agg_out<<<(NNODES + 3) / 4, 256, 0, stream>>>(xr, qp, kp, offs, pk, bl[l],
                                                    houts[l], NNODES, l < 2 ? 1 : 0);
    hin = houts[l];
  }
}